// Round 7
// baseline (486.408 us; speedup 1.0000x reference)
//
#include <hip/hip_runtime.h>
#include <hip/hip_bf16.h>
#include <stdint.h>

#define S_LEN 4096

typedef short s16x8  __attribute__((ext_vector_type(8)));
typedef float f32x4  __attribute__((ext_vector_type(4)));
typedef float f32x16 __attribute__((ext_vector_type(16)));

// log2(e)/8 : folded into Q at QKV epilogue; attn does exp2(score) directly
#define CEXP 0.18033688011112042f

__device__ __forceinline__ unsigned short f2bf(float f) {
    union { float f; unsigned u; } v; v.f = f;
    unsigned r = v.u + 0x7fffu + ((v.u >> 16) & 1u);
    return (unsigned short)(r >> 16);
}

__device__ __forceinline__ ushort2 pkbf(float a, float b) {
    float2 f; f.x = a; f.y = b;
    __hip_bfloat162 h = __float22bfloat162_rn(f);
    union { __hip_bfloat162 h; ushort2 u; } cv; cv.h = h;
    return cv.u;
}

__device__ __forceinline__ ushort4 pkbf4(float x, float y, float z, float w) {
    ushort2 lo = pkbf(x, y), hi = pkbf(z, w);
    ushort4 r; r.x = lo.x; r.y = lo.y; r.z = hi.x; r.w = hi.y;
    return r;
}

typedef const __attribute__((address_space(1))) void* gas_t;
typedef __attribute__((address_space(3))) void* sas_t;

__device__ __forceinline__ void async16(const void* g, void* s) {
    __builtin_amdgcn_global_load_lds((gas_t)g, (sas_t)s, 16, 0, 0);
}

// ---------------------------------------------------------------------------
// fp32 -> bf16 convert for X (4194304) and W (3145728). 8 elems/thread.
// ---------------------------------------------------------------------------
__global__ __launch_bounds__(256) void cvt_bf16(
    const float* __restrict__ X, const float* __restrict__ W,
    unsigned short* __restrict__ Xb, unsigned short* __restrict__ Wb)
{
    const long NX = 4194304;
    long i = (long)(blockIdx.x * 256 + threadIdx.x) * 8;
    const float* src; unsigned short* dst; long off;
    if (i < NX) { src = X; dst = Xb; off = i; }
    else        { src = W; dst = Wb; off = i - NX; }
    float4 a = *(const float4*)(src + off);
    float4 b = *(const float4*)(src + off + 4);
    union { s16x8 v; ushort4 q[2]; } o;
    o.q[0] = pkbf4(a.x, a.y, a.z, a.w);
    o.q[1] = pkbf4(b.x, b.y, b.z, b.w);
    *(s16x8*)(dst + off) = o.v;
}

// ---------------------------------------------------------------------------
// Kernel A (primary): qkv = Xb @ Wb^T + b, bf16 in, m97-style staging.
// 128x128 tile, BK=64, global_load_lds width-16, mfma 16x16x32.
// XCD swizzle: xcd=bid%8 owns bn strip {3*xcd..3*xcd+2}.
// Q pre-scaled by CEXP; V columns pre-scaled by trace diagonal.
// Q,K -> [h][s][d] (via LDS transpose, 16B stores); V -> [h][d][s].
// ---------------------------------------------------------------------------
__global__ __launch_bounds__(256) void qkv_gemm_bf16(
    const unsigned short* __restrict__ Xb, const unsigned short* __restrict__ Wb,
    const float* __restrict__ bias, const float* __restrict__ trace,
    unsigned short* __restrict__ Qb, unsigned short* __restrict__ Kb,
    unsigned short* __restrict__ Vt)
{
    __shared__ __align__(16) unsigned short sm[17408];   // 34816 B
    unsigned short* As = sm;            // [128][64] bf16, unpadded (async dst)
    unsigned short* Bs = sm + 8192;     // [128][64]

    const int t = threadIdx.x;
    const int l = t & 63;
    const int w = t >> 6;
    const int bid = blockIdx.x;
    const int xcd = bid & 7;
    const int ii  = bid >> 3;          // 0..95
    const int bn  = 3 * xcd + (ii % 3);
    const int bm  = ii / 3;
    const int rowBase = (w >> 1) * 64;
    const int colBase = (w & 1) * 64;

    f32x4 acc[4][4];
#pragma unroll
    for (int i = 0; i < 4; i++)
#pragma unroll
        for (int j = 0; j < 4; j++) acc[i][j] = (f32x4)0.f;

    const int srow = l >> 3;        // 0..7
    const int scol = (l & 7) * 8;   // shorts

    for (int kt = 0; kt < 16; ++kt) {
        const int k0 = kt * 64;
#pragma unroll
        for (int c = 0; c < 4; ++c) {
            int m = w * 4 + c;                    // chunk 0..15 (8 rows each)
            const unsigned short* ga = Xb + (bm * 128 + m * 8 + srow) * 1024 + k0 + scol;
            const unsigned short* gb = Wb + (bn * 128 + m * 8 + srow) * 1024 + k0 + scol;
            async16(ga, As + m * 512);
            async16(gb, Bs + m * 512);
        }
        __syncthreads();

#pragma unroll
        for (int kc = 0; kc < 2; ++kc) {
            s16x8 af[4], bf[4];
#pragma unroll
            for (int i = 0; i < 4; i++) {
                af[i] = *(const s16x8*)(As + (rowBase + i * 16 + (l & 15)) * 64 + kc * 32 + (l >> 4) * 8);
                bf[i] = *(const s16x8*)(Bs + (colBase + i * 16 + (l & 15)) * 64 + kc * 32 + (l >> 4) * 8);
            }
#pragma unroll
            for (int i = 0; i < 4; i++)
#pragma unroll
                for (int j = 0; j < 4; j++)
                    acc[i][j] = __builtin_amdgcn_mfma_f32_16x16x32_bf16(af[i], bf[j], acc[i][j], 0, 0, 0);
        }
        __syncthreads();
    }

    if (bn < 16) {
        __syncthreads();
        unsigned short* Lt = sm;              // [128][136]
        const int region = bn >> 3;           // 0=Q, 1=K
        const float scl = (region == 0) ? CEXP : 1.0f;
#pragma unroll
        for (int j = 0; j < 4; j++) {
            int cl = colBase + j * 16 + (l & 15);
            float bv = bias[bn * 128 + cl];
#pragma unroll
            for (int i = 0; i < 4; i++) {
                int s0 = rowBase + i * 16 + ((l >> 4) << 2);
#pragma unroll
                for (int r = 0; r < 4; r++)
                    Lt[(s0 + r) * 136 + cl] = f2bf((acc[i][j][r] + bv) * scl);
            }
        }
        __syncthreads();
        unsigned short* dst = (region == 0) ? Qb : Kb;
        const int h0 = (bn & 7) * 2;
#pragma unroll
        for (int p = 0; p < 8; ++p) {
            int linear = p * 256 + t;
            int sl = linear >> 4;             // 0..127
            int ch = linear & 15;
            int d  = (ch & 7) * 8;
            int h  = h0 + (ch >> 3);
            s16x8 v = *(const s16x8*)(Lt + sl * 136 + ch * 8);
            *(s16x8*)(dst + (h * S_LEN + bm * 128 + sl) * 64 + d) = v;
        }
    } else {
        __syncthreads();
        unsigned short* Lt = sm;              // [128][136]
#pragma unroll
        for (int j = 0; j < 4; j++) {
            int cl = colBase + j * 16 + (l & 15);
            int o  = bn * 128 + cl - 2048;     // 0..1023 within V
            float bv = bias[bn * 128 + cl];
            float tr = trace[(o >> 6) * 4096 + (o & 63) * 65];
#pragma unroll
            for (int i = 0; i < 4; i++) {
                int s0 = rowBase + i * 16 + ((l >> 4) << 2);
                *(ushort4*)(Lt + cl * 136 + s0) =
                    pkbf4((acc[i][j][0] + bv) * tr, (acc[i][j][1] + bv) * tr,
                          (acc[i][j][2] + bv) * tr, (acc[i][j][3] + bv) * tr);
            }
        }
        __syncthreads();
#pragma unroll
        for (int p = 0; p < 8; ++p) {
            int dl  = (t >> 4) + p * 16;
            int sch = (t & 15) * 8;
            int o = bn * 128 + dl - 2048;
            int h = o >> 6, d = o & 63;
            s16x8 v = *(const s16x8*)(Lt + dl * 136 + sch);
            *(s16x8*)(Vt + (h * 64 + d) * S_LEN + bm * 128 + sch) = v;
        }
    }
}

// ---------------------------------------------------------------------------
// Kernel A (fallback, small ws): fp32-staged GEMM, same outputs
// ---------------------------------------------------------------------------
__global__ __launch_bounds__(256) void qkv_gemm_f32(
    const float* __restrict__ X, const float* __restrict__ W,
    const float* __restrict__ bias, const float* __restrict__ trace,
    unsigned short* __restrict__ Qb, unsigned short* __restrict__ Kb,
    unsigned short* __restrict__ Vt)
{
    __shared__ __align__(16) unsigned short sm[17408];
    unsigned short* As = sm;
    unsigned short* Bs = sm + 5120;

    const int t = threadIdx.x;
    const int l = t & 63;
    const int w = t >> 6;
    const int bm = blockIdx.y, bn = blockIdx.x;
    const int rowBase = (w >> 1) * 64;
    const int colBase = (w & 1) * 64;

    f32x4 acc[4][4];
#pragma unroll
    for (int i = 0; i < 4; i++)
#pragma unroll
        for (int j = 0; j < 4; j++) acc[i][j] = (f32x4)0.f;

    const int sr = t >> 3;
    const int sc = (t & 7) * 4;

    for (int kt = 0; kt < 32; ++kt) {
        const int k0 = kt * 32;
#pragma unroll
        for (int p = 0; p < 4; ++p) {
            int r = sr + p * 32;
            float4 xa = *(const float4*)(X + (bm * 128 + r) * 1024 + k0 + sc);
            float4 wb = *(const float4*)(W + (bn * 128 + r) * 1024 + k0 + sc);
            *(ushort4*)(As + r * 40 + sc) = pkbf4(xa.x, xa.y, xa.z, xa.w);
            *(ushort4*)(Bs + r * 40 + sc) = pkbf4(wb.x, wb.y, wb.z, wb.w);
        }
        __syncthreads();

        s16x8 af[4], bf[4];
#pragma unroll
        for (int i = 0; i < 4; i++) {
            af[i] = *(const s16x8*)(As + (rowBase + i * 16 + (l & 15)) * 40 + (l >> 4) * 8);
            bf[i] = *(const s16x8*)(Bs + (colBase + i * 16 + (l & 15)) * 40 + (l >> 4) * 8);
        }
#pragma unroll
        for (int i = 0; i < 4; i++)
#pragma unroll
            for (int j = 0; j < 4; j++)
                acc[i][j] = __builtin_amdgcn_mfma_f32_16x16x32_bf16(af[i], bf[j], acc[i][j], 0, 0, 0);
        __syncthreads();
    }

    if (bn < 16) {
        __syncthreads();
        unsigned short* Lt = sm;
        const int region = bn >> 3;
        const float scl = (region == 0) ? CEXP : 1.0f;
#pragma unroll
        for (int j = 0; j < 4; j++) {
            int cl = colBase + j * 16 + (l & 15);
            float bv = bias[bn * 128 + cl];
#pragma unroll
            for (int i = 0; i < 4; i++) {
                int s0 = rowBase + i * 16 + ((l >> 4) << 2);
#pragma unroll
                for (int r = 0; r < 4; r++)
                    Lt[(s0 + r) * 136 + cl] = f2bf((acc[i][j][r] + bv) * scl);
            }
        }
        __syncthreads();
        unsigned short* dst = (region == 0) ? Qb : Kb;
        const int h0 = (bn & 7) * 2;
#pragma unroll
        for (int p = 0; p < 8; ++p) {
            int linear = p * 256 + t;
            int sl = linear >> 4;
            int ch = linear & 15;
            int d  = (ch & 7) * 8;
            int h  = h0 + (ch >> 3);
            s16x8 v = *(const s16x8*)(Lt + sl * 136 + ch * 8);
            *(s16x8*)(dst + (h * S_LEN + bm * 128 + sl) * 64 + d) = v;
        }
    } else {
        __syncthreads();
        unsigned short* Lt = sm;
#pragma unroll
        for (int j = 0; j < 4; j++) {
            int cl = colBase + j * 16 + (l & 15);
            int o  = bn * 128 + cl - 2048;
            float bv = bias[bn * 128 + cl];
            float tr = trace[(o >> 6) * 4096 + (o & 63) * 65];
#pragma unroll
            for (int i = 0; i < 4; i++) {
                int s0 = rowBase + i * 16 + ((l >> 4) << 2);
                *(ushort4*)(Lt + cl * 136 + s0) =
                    pkbf4((acc[i][j][0] + bv) * tr, (acc[i][j][1] + bv) * tr,
                          (acc[i][j][2] + bv) * tr, (acc[i][j][3] + bv) * tr);
            }
        }
        __syncthreads();
#pragma unroll
        for (int p = 0; p < 8; ++p) {
            int dl  = (t >> 4) + p * 16;
            int sch = (t & 15) * 8;
            int o = bn * 128 + dl - 2048;
            int h = o >> 6, d = o & 63;
            s16x8 v = *(const s16x8*)(Lt + dl * 136 + sch);
            *(s16x8*)(Vt + (h * 64 + d) * S_LEN + bm * 128 + sch) = v;
        }
    }
}

// ---------------------------------------------------------------------------
// Kernel B: flash attention, S^T trick, fixed m=0, in-block kv-split.
// SMALL BLOCKS for overlap: 256 thr = 2 kv-groups x 2 q-waves, q-tile 64,
// grid 1024 -> 4 INDEPENDENT blocks/CU (16 waves/CU in 4 barrier domains:
// one block's staging barrier overlaps three others' compute).
// LDS 40 KB: K/V staged at stride 68 (2-way banks = free), wave-private
// 32x20 P chunk (R6-proven), epilogue Lo unioned over staging area.
// V carries the trace diagonal; output needs only 1/l.
// ---------------------------------------------------------------------------
__global__ __launch_bounds__(256, 4) void attn(
    const unsigned short* __restrict__ Qb, const unsigned short* __restrict__ Kb,
    const unsigned short* __restrict__ Vt, float* __restrict__ out)
{
    __shared__ __align__(16) unsigned short sm[19968];   // 39936 B
    __shared__ float lArr[64];

    const int t = threadIdx.x;
    const int l = t & 63;
    const int w = t >> 6;            // 0..3
    const int g = w >> 1;            // kv half
    const int wq = w & 1;            // q sub-tile
    const int h = blockIdx.y;
    const int qbase = blockIdx.x * 64 + wq * 32;
    const int l31 = l & 31;
    const int lh  = l >> 5;

    unsigned short* Ks  = sm + g * 8704;          // [64][68] : [kv][d]
    unsigned short* Vts = sm + g * 8704 + 4352;   // [64][68] : [d][kv]
    unsigned short* Pc  = sm + 17408 + w * 640;   // [32][20] wave-private

    // Q B-operand fragments
    s16x8 qf[4];
#pragma unroll
    for (int ks = 0; ks < 4; ks++)
        qf[ks] = *(const s16x8*)(Qb + (h * S_LEN + qbase + l31) * 64 + ks * 16 + lh * 8);

    f32x16 O0 = (f32x16)0.f, O1 = (f32x16)0.f;
    float2 lpA; lpA.x = 0.f; lpA.y = 0.f;
    float2 lpB; lpB.x = 0.f; lpB.y = 0.f;

    // staging: 128 threads per group cover 64 rows x 128 B (2 thr/row, 64 B each)
    const int tg    = t & 127;
    const int strow = tg >> 1;           // 0..63
    const int stcol = (tg & 1) * 32;     // shorts

    const unsigned short* kR = Kb + (h * S_LEN + g * 2048 + strow) * 64 + stcol;
    const unsigned short* vR = Vt + (h * 64 + strow) * S_LEN + g * 2048 + stcol;

    for (int kt = 0; kt < 32; ++kt) {
        {
            const unsigned short* ks_ = kR + kt * 4096;   // +64 kv rows
            const unsigned short* vs_ = vR + kt * 64;     // +64 kv cols
            s16x8 k0 = *(const s16x8*)(ks_);
            s16x8 k1 = *(const s16x8*)(ks_ + 8);
            s16x8 k2 = *(const s16x8*)(ks_ + 16);
            s16x8 k3 = *(const s16x8*)(ks_ + 24);
            s16x8 v0 = *(const s16x8*)(vs_);
            s16x8 v1 = *(const s16x8*)(vs_ + 8);
            s16x8 v2 = *(const s16x8*)(vs_ + 16);
            s16x8 v3 = *(const s16x8*)(vs_ + 24);
            unsigned short* kw = Ks  + strow * 68 + stcol;
            unsigned short* vw = Vts + strow * 68 + stcol;
            *(s16x8*)(kw)      = k0;
            *(s16x8*)(kw + 8)  = k1;
            *(s16x8*)(kw + 16) = k2;
            *(s16x8*)(kw + 24) = k3;
            *(s16x8*)(vw)      = v0;
            *(s16x8*)(vw + 8)  = v1;
            *(s16x8*)(vw + 16) = v2;
            *(s16x8*)(vw + 24) = v3;
        }
        __syncthreads();

        // S^T[kv][q] = K x Q^T  (scores pre-scaled via Q)
        f32x16 S0 = (f32x16)0.f, S1 = (f32x16)0.f;
#pragma unroll
        for (int ks = 0; ks < 4; ++ks) {
            s16x8 a0 = *(const s16x8*)(Ks + l31 * 68 + ks * 16 + lh * 8);
            s16x8 a1 = *(const s16x8*)(Ks + (32 + l31) * 68 + ks * 16 + lh * 8);
            S0 = __builtin_amdgcn_mfma_f32_32x32x16_bf16(a0, qf[ks], S0, 0, 0, 0);
            S1 = __builtin_amdgcn_mfma_f32_32x32x16_bf16(a1, qf[ks], S1, 0, 0, 0);
        }

        // p = exp2(score), lane-local sums
#pragma unroll
        for (int i = 0; i < 16; i += 4) {
            float p0 = __builtin_amdgcn_exp2f(S0[i+0]); S0[i+0] = p0; lpA.x += p0;
            float p1 = __builtin_amdgcn_exp2f(S0[i+1]); S0[i+1] = p1; lpA.y += p1;
            float p2 = __builtin_amdgcn_exp2f(S0[i+2]); S0[i+2] = p2; lpB.x += p2;
            float p3 = __builtin_amdgcn_exp2f(S0[i+3]); S0[i+3] = p3; lpB.y += p3;
        }
#pragma unroll
        for (int i = 0; i < 16; i += 4) {
            float p0 = __builtin_amdgcn_exp2f(S1[i+0]); S1[i+0] = p0; lpA.x += p0;
            float p1 = __builtin_amdgcn_exp2f(S1[i+1]); S1[i+1] = p1; lpA.y += p1;
            float p2 = __builtin_amdgcn_exp2f(S1[i+2]); S1[i+2] = p2; lpB.x += p2;
            float p3 = __builtin_amdgcn_exp2f(S1[i+3]); S1[i+3] = p3; lpB.y += p3;
        }

        // PV per 16-kv chunk: wave-private P through LDS, V from LDS
#pragma unroll
        for (int ks = 0; ks < 4; ++ks) {
            ushort4 qL, qH;
            if (ks == 0) {
                qL = pkbf4(S0[0], S0[1], S0[2], S0[3]);
                qH = pkbf4(S0[4], S0[5], S0[6], S0[7]);
            } else if (ks == 1) {
                qL = pkbf4(S0[8], S0[9], S0[10], S0[11]);
                qH = pkbf4(S0[12], S0[13], S0[14], S0[15]);
            } else if (ks == 2) {
                qL = pkbf4(S1[0], S1[1], S1[2], S1[3]);
                qH = pkbf4(S1[4], S1[5], S1[6], S1[7]);
            } else {
                qL = pkbf4(S1[8], S1[9], S1[10], S1[11]);
                qH = pkbf4(S1[12], S1[13], S1[14], S1[15]);
            }
            *(ushort4*)(Pc + l31 * 20 + 4 * lh)     = qL;
            *(ushort4*)(Pc + l31 * 20 + 8 + 4 * lh) = qH;

            union { s16x8 v; ushort4 q[2]; } pu;
            pu.q[0] = *(const ushort4*)(Pc + l31 * 20 + lh * 8);
            pu.q[1] = *(const ushort4*)(Pc + l31 * 20 + lh * 8 + 4);

            s16x8 av0 = *(const s16x8*)(Vts + l31 * 68 + ks * 16 + lh * 8);
            s16x8 av1 = *(const s16x8*)(Vts + (32 + l31) * 68 + ks * 16 + lh * 8);
            O0 = __builtin_amdgcn_mfma_f32_32x32x16_bf16(av0, pu.v, O0, 0, 0, 0);
            O1 = __builtin_amdgcn_mfma_f32_32x32x16_bf16(av1, pu.v, O1, 0, 0, 0);
        }
        __syncthreads();
    }

    // l over this wave's kv-half for q = qbase + l31
    float l_part = (lpA.x + lpA.y) + (lpB.x + lpB.y);
    float l_tot = l_part + __shfl_xor(l_part, 32);

    float* Lo = (float*)sm;              // 2 slots x 32 q x 68 floats (union)
    if (g == 1) {
        if (lh == 0) lArr[wq * 32 + l31] = l_tot;
        float* Ls = Lo + wq * 2176;
#pragma unroll
        for (int dt = 0; dt < 2; ++dt) {
            const f32x16& Ox = dt ? O1 : O0;
#pragma unroll
            for (int gq = 0; gq < 4; ++gq) {
                int d0 = dt * 32 + gq * 8 + lh * 4;
                float4 vv;
                vv.x = Ox[gq*4+0]; vv.y = Ox[gq*4+1]; vv.z = Ox[gq*4+2]; vv.w = Ox[gq*4+3];
                *(float4*)(Ls + l31 * 68 + d0) = vv;
            }
        }
    }
    __syncthreads();
    if (g == 0) {
        float invl = 1.0f / (l_tot + lArr[wq * 32 + l31]);
        float* Ls = Lo + wq * 2176;
#pragma unroll
        for (int dt = 0; dt < 2; ++dt) {
            const f32x16& Ox = dt ? O1 : O0;
#pragma unroll
            for (int gq = 0; gq < 4; ++gq) {
                int d0 = dt * 32 + gq * 8 + lh * 4;
                float4 p = *(const float4*)(Ls + l31 * 68 + d0);
                p.x = (p.x + Ox[gq*4+0]) * invl;
                p.y = (p.y + Ox[gq*4+1]) * invl;
                p.z = (p.z + Ox[gq*4+2]) * invl;
                p.w = (p.w + Ox[gq*4+3]) * invl;
                *(float4*)(Ls + l31 * 68 + d0) = p;
            }
        }
    }
    __syncthreads();
#pragma unroll
    for (int it = 0; it < 4; ++it) {
        int linear = it * 256 + t;          // 0..1023
        int row = linear >> 4;              // q-local 0..63
        int c   = (linear & 15) * 4;        // d0
        float4 v = *(const float4*)(Lo + (row >> 5) * 2176 + (row & 31) * 68 + c);
        *(float4*)(out + (blockIdx.x * 64 + row) * 1024 + h * 64 + c) = v;
    }
}

extern "C" void kernel_launch(void* const* d_in, const int* in_sizes, int n_in,
                              void* d_out, int out_size, void* d_ws, size_t ws_size,
                              hipStream_t stream) {
    const float* X     = (const float*)d_in[0];   // [1,4096,1024]
    const float* W     = (const float*)d_in[1];   // [3072,1024]
    const float* bias  = (const float*)d_in[2];   // [3072]
    const float* trace = (const float*)d_in[3];   // [16,64,64]
    float* out = (float*)d_out;

    unsigned short* Qb = (unsigned short*)d_ws;            // 8 MiB [h][s][d] (pre-scaled by CEXP)
    unsigned short* Kb = Qb + 4194304;                     // 8 MiB [h][s][d]
    unsigned short* Vt = Kb + 4194304;                     // 8 MiB [h][d][s] (pre-scaled by trace diag)
    unsigned short* Xb = Vt + 4194304;                     // 8 MiB bf16 X
    unsigned short* Wb = Xb + 4194304;                     // 6 MiB bf16 W

    const size_t NEED_BF16 = (size_t)3 * 8388608 + 8388608 + 6291456;

    if (ws_size >= NEED_BF16) {
        cvt_bf16<<<3584, 256, 0, stream>>>(X, W, Xb, Wb);
        qkv_gemm_bf16<<<768, 256, 0, stream>>>(Xb, Wb, bias, trace, Qb, Kb, Vt);
    } else {
        qkv_gemm_f32<<<dim3(24, 32), 256, 0, stream>>>(X, W, bias, trace, Qb, Kb, Vt);
    }
    attn<<<dim3(64, 16), 256, 0, stream>>>(Qb, Kb, Vt, out);
}

// Round 8
// 212.683 us; speedup vs baseline: 2.2870x; 2.2870x over previous
//
#include <hip/hip_runtime.h>
#include <hip/hip_bf16.h>
#include <stdint.h>

#define S_LEN 4096

typedef short s16x8  __attribute__((ext_vector_type(8)));
typedef float f32x4  __attribute__((ext_vector_type(4)));
typedef float f32x16 __attribute__((ext_vector_type(16)));

// log2(e)/8 : folded into Q at QKV epilogue; attn does exp2(score) directly
#define CEXP 0.18033688011112042f

__device__ __forceinline__ unsigned short f2bf(float f) {
    union { float f; unsigned u; } v; v.f = f;
    unsigned r = v.u + 0x7fffu + ((v.u >> 16) & 1u);
    return (unsigned short)(r >> 16);
}

__device__ __forceinline__ ushort2 pkbf(float a, float b) {
    float2 f; f.x = a; f.y = b;
    __hip_bfloat162 h = __float22bfloat162_rn(f);
    union { __hip_bfloat162 h; ushort2 u; } cv; cv.h = h;
    return cv.u;
}

__device__ __forceinline__ ushort4 pkbf4(float x, float y, float z, float w) {
    ushort2 lo = pkbf(x, y), hi = pkbf(z, w);
    ushort4 r; r.x = lo.x; r.y = lo.y; r.z = hi.x; r.w = hi.y;
    return r;
}

typedef const __attribute__((address_space(1))) void* gas_t;
typedef __attribute__((address_space(3))) void* sas_t;

__device__ __forceinline__ void async16(const void* g, void* s) {
    __builtin_amdgcn_global_load_lds((gas_t)g, (sas_t)s, 16, 0, 0);
}

// ---------------------------------------------------------------------------
// fp32 -> bf16 convert for X (4194304) and W (3145728). 8 elems/thread.
// ---------------------------------------------------------------------------
__global__ __launch_bounds__(256) void cvt_bf16(
    const float* __restrict__ X, const float* __restrict__ W,
    unsigned short* __restrict__ Xb, unsigned short* __restrict__ Wb)
{
    const long NX = 4194304;
    long i = (long)(blockIdx.x * 256 + threadIdx.x) * 8;
    const float* src; unsigned short* dst; long off;
    if (i < NX) { src = X; dst = Xb; off = i; }
    else        { src = W; dst = Wb; off = i - NX; }
    float4 a = *(const float4*)(src + off);
    float4 b = *(const float4*)(src + off + 4);
    union { s16x8 v; ushort4 q[2]; } o;
    o.q[0] = pkbf4(a.x, a.y, a.z, a.w);
    o.q[1] = pkbf4(b.x, b.y, b.z, b.w);
    *(s16x8*)(dst + off) = o.v;
}

// ---------------------------------------------------------------------------
// Kernel A (primary): qkv = Xb @ Wb^T + b, bf16 in, m97-style staging.
// 128x128 tile, BK=64, global_load_lds width-16, mfma 16x16x32.
// dim3(24,32): 24 = 3x8 -> W-strip x lands on XCD x%8 consistently across
// bm (per-XCD Wb slice 0.75MB stays L2-resident) - already XCD-optimal.
// Q pre-scaled by CEXP; V columns pre-scaled by trace diagonal (exact:
// (P.V)*t == P.(V*t)). Q,K -> [h][s][d]; V -> transposed [h][d][s].
// ---------------------------------------------------------------------------
__global__ __launch_bounds__(256) void qkv_gemm_bf16(
    const unsigned short* __restrict__ Xb, const unsigned short* __restrict__ Wb,
    const float* __restrict__ bias, const float* __restrict__ trace,
    unsigned short* __restrict__ Qb, unsigned short* __restrict__ Kb,
    unsigned short* __restrict__ Vt)
{
    __shared__ __align__(16) unsigned short sm[17408];   // 34816 B
    unsigned short* As = sm;            // [128][64] bf16, unpadded (async dst)
    unsigned short* Bs = sm + 8192;     // [128][64]

    const int t = threadIdx.x;
    const int l = t & 63;
    const int w = t >> 6;
    const int bm = blockIdx.y, bn = blockIdx.x;
    const int rowBase = (w >> 1) * 64;
    const int colBase = (w & 1) * 64;

    f32x4 acc[4][4];
#pragma unroll
    for (int i = 0; i < 4; i++)
#pragma unroll
        for (int j = 0; j < 4; j++) acc[i][j] = (f32x4)0.f;

    const int srow = l >> 3;        // 0..7
    const int scol = (l & 7) * 8;   // shorts

    for (int kt = 0; kt < 16; ++kt) {
        const int k0 = kt * 64;
#pragma unroll
        for (int c = 0; c < 4; ++c) {
            int m = w * 4 + c;                    // chunk 0..15 (8 rows each)
            const unsigned short* ga = Xb + (bm * 128 + m * 8 + srow) * 1024 + k0 + scol;
            const unsigned short* gb = Wb + (bn * 128 + m * 8 + srow) * 1024 + k0 + scol;
            async16(ga, As + m * 512);
            async16(gb, Bs + m * 512);
        }
        __syncthreads();

#pragma unroll
        for (int kc = 0; kc < 2; ++kc) {
            s16x8 af[4], bf[4];
#pragma unroll
            for (int i = 0; i < 4; i++) {
                af[i] = *(const s16x8*)(As + (rowBase + i * 16 + (l & 15)) * 64 + kc * 32 + (l >> 4) * 8);
                bf[i] = *(const s16x8*)(Bs + (colBase + i * 16 + (l & 15)) * 64 + kc * 32 + (l >> 4) * 8);
            }
#pragma unroll
            for (int i = 0; i < 4; i++)
#pragma unroll
                for (int j = 0; j < 4; j++)
                    acc[i][j] = __builtin_amdgcn_mfma_f32_16x16x32_bf16(af[i], bf[j], acc[i][j], 0, 0, 0);
        }
        __syncthreads();
    }

    if (bn < 16) {
#pragma unroll
        for (int j = 0; j < 4; j++) {
            int col = bn * 128 + colBase + j * 16 + (l & 15);
            float bv = bias[col];
            int region = col >> 10;            // 0=Q, 1=K
            int within = col & 1023;
            int h = within >> 6, d = within & 63;
            unsigned short* dst = (region == 0) ? Qb : Kb;
            float scl = (region == 0) ? CEXP : 1.0f;
#pragma unroll
            for (int i = 0; i < 4; i++) {
                int s0 = bm * 128 + rowBase + i * 16 + ((l >> 4) << 2);
#pragma unroll
                for (int r = 0; r < 4; r++)
                    dst[(h * S_LEN + s0 + r) * 64 + d] = f2bf((acc[i][j][r] + bv) * scl);
            }
        }
    } else {
        __syncthreads();
        unsigned short* Lt = sm;              // 128 x 136
#pragma unroll
        for (int j = 0; j < 4; j++) {
            int cl = colBase + j * 16 + (l & 15);
            int o  = bn * 128 + cl - 2048;     // 0..1023 within V
            float bv = bias[bn * 128 + cl];
            float tr = trace[(o >> 6) * 4096 + (o & 63) * 65];
#pragma unroll
            for (int i = 0; i < 4; i++) {
                int s0 = rowBase + i * 16 + ((l >> 4) << 2);
                *(ushort4*)(Lt + cl * 136 + s0) =
                    pkbf4((acc[i][j][0] + bv) * tr, (acc[i][j][1] + bv) * tr,
                          (acc[i][j][2] + bv) * tr, (acc[i][j][3] + bv) * tr);
            }
        }
        __syncthreads();
#pragma unroll
        for (int p = 0; p < 8; ++p) {
            int dl  = (t >> 4) + p * 16;
            int sch = (t & 15) * 8;
            int o = bn * 128 + dl - 2048;
            int h = o >> 6, d = o & 63;
            s16x8 v = *(const s16x8*)(Lt + dl * 136 + sch);
            *(s16x8*)(Vt + (h * 64 + d) * S_LEN + bm * 128 + sch) = v;
        }
    }
}

// ---------------------------------------------------------------------------
// Kernel A (fallback, small ws): fp32-staged GEMM, same outputs
// ---------------------------------------------------------------------------
__global__ __launch_bounds__(256) void qkv_gemm_f32(
    const float* __restrict__ X, const float* __restrict__ W,
    const float* __restrict__ bias, const float* __restrict__ trace,
    unsigned short* __restrict__ Qb, unsigned short* __restrict__ Kb,
    unsigned short* __restrict__ Vt)
{
    __shared__ __align__(16) unsigned short sm[17408];
    unsigned short* As = sm;
    unsigned short* Bs = sm + 5120;

    const int t = threadIdx.x;
    const int l = t & 63;
    const int w = t >> 6;
    const int bm = blockIdx.y, bn = blockIdx.x;
    const int rowBase = (w >> 1) * 64;
    const int colBase = (w & 1) * 64;

    f32x4 acc[4][4];
#pragma unroll
    for (int i = 0; i < 4; i++)
#pragma unroll
        for (int j = 0; j < 4; j++) acc[i][j] = (f32x4)0.f;

    const int sr = t >> 3;
    const int sc = (t & 7) * 4;

    for (int kt = 0; kt < 32; ++kt) {
        const int k0 = kt * 32;
#pragma unroll
        for (int p = 0; p < 4; ++p) {
            int r = sr + p * 32;
            float4 xa = *(const float4*)(X + (bm * 128 + r) * 1024 + k0 + sc);
            float4 wb = *(const float4*)(W + (bn * 128 + r) * 1024 + k0 + sc);
            *(ushort4*)(As + r * 40 + sc) = pkbf4(xa.x, xa.y, xa.z, xa.w);
            *(ushort4*)(Bs + r * 40 + sc) = pkbf4(wb.x, wb.y, wb.z, wb.w);
        }
        __syncthreads();

        s16x8 af[4], bf[4];
#pragma unroll
        for (int i = 0; i < 4; i++) {
            af[i] = *(const s16x8*)(As + (rowBase + i * 16 + (l & 15)) * 40 + (l >> 4) * 8);
            bf[i] = *(const s16x8*)(Bs + (colBase + i * 16 + (l & 15)) * 40 + (l >> 4) * 8);
        }
#pragma unroll
        for (int i = 0; i < 4; i++)
#pragma unroll
            for (int j = 0; j < 4; j++)
                acc[i][j] = __builtin_amdgcn_mfma_f32_16x16x32_bf16(af[i], bf[j], acc[i][j], 0, 0, 0);
        __syncthreads();
    }

    if (bn < 16) {
#pragma unroll
        for (int j = 0; j < 4; j++) {
            int col = bn * 128 + colBase + j * 16 + (l & 15);
            float bv = bias[col];
            int region = col >> 10;
            int within = col & 1023;
            int h = within >> 6, d = within & 63;
            unsigned short* dst = (region == 0) ? Qb : Kb;
            float scl = (region == 0) ? CEXP : 1.0f;
#pragma unroll
            for (int i = 0; i < 4; i++) {
                int s0 = bm * 128 + rowBase + i * 16 + ((l >> 4) << 2);
#pragma unroll
                for (int r = 0; r < 4; r++)
                    dst[(h * S_LEN + s0 + r) * 64 + d] = f2bf((acc[i][j][r] + bv) * scl);
            }
        }
    } else {
        __syncthreads();
        unsigned short* Lt = sm;
#pragma unroll
        for (int j = 0; j < 4; j++) {
            int cl = colBase + j * 16 + (l & 15);
            int o  = bn * 128 + cl - 2048;
            float bv = bias[bn * 128 + cl];
            float tr = trace[(o >> 6) * 4096 + (o & 63) * 65];
#pragma unroll
            for (int i = 0; i < 4; i++) {
                int s0 = rowBase + i * 16 + ((l >> 4) << 2);
                *(ushort4*)(Lt + cl * 136 + s0) =
                    pkbf4((acc[i][j][0] + bv) * tr, (acc[i][j][1] + bv) * tr,
                          (acc[i][j][2] + bv) * tr, (acc[i][j][3] + bv) * tr);
            }
        }
        __syncthreads();
#pragma unroll
        for (int p = 0; p < 8; ++p) {
            int dl  = (t >> 4) + p * 16;
            int sch = (t & 15) * 8;
            int o = bn * 128 + dl - 2048;
            int h = o >> 6, d = o & 63;
            s16x8 v = *(const s16x8*)(Lt + dl * 136 + sch);
            *(s16x8*)(Vt + (h * 64 + d) * S_LEN + bm * 128 + sch) = v;
        }
    }
}

// ---------------------------------------------------------------------------
// Kernel B: flash attention (R4-verified structure), S^T trick, fixed m=0,
// in-block kv-split: 512 thr = 2 wave-groups x 4 waves; group g covers kv
// half g of the same 128-q tile; combine in LDS at the end.
// NEW vs R4: XCD head-grouping swizzle - xcd=bid%8 owns heads {2x,2x+1},
// so each XCD's K+V working set is 2MB (L2-resident) instead of 16MB.
// K/V staged at stride 72 (16B-aligned rows - REQUIRED for ds_read_b128);
// P batched to Ps rows (stride 68 shorts, 8B-aligned ushort4 accesses).
// V carries the trace diagonal; output needs only 1/l.
// ---------------------------------------------------------------------------
__global__ __launch_bounds__(512, 4) void attn(
    const unsigned short* __restrict__ Qb, const unsigned short* __restrict__ Kb,
    const unsigned short* __restrict__ Vt, float* __restrict__ out)
{
    __shared__ __align__(16) unsigned short sm[35840];   // 71680 B
    __shared__ float lArr[256];

    const int t = threadIdx.x;
    const int l = t & 63;
    const int w = t >> 6;            // 0..7
    const int g = w >> 2;            // kv half
    const int wq = w & 3;            // q sub-tile
    // XCD swizzle: xcd = bid%8 owns heads {2*xcd, 2*xcd+1}
    const int bid = blockIdx.x;
    const int xcd = bid & 7;
    const int j   = bid >> 3;        // 0..63
    const int h   = xcd * 2 + (j & 1);
    const int qblk = j >> 1;         // 0..31
    const int qbase = qblk * 128 + wq * 32;
    const int l31 = l & 31;
    const int lh  = l >> 5;

    unsigned short* Ks  = sm + g * 9216;          // [64][72] : [kv][d]
    unsigned short* Vts = sm + g * 9216 + 4608;   // [64][72] : [d][kv]
    unsigned short* Pw  = sm + 18432 + w * 2176 + l31 * 68;

    s16x8 qf[4];
#pragma unroll
    for (int ks = 0; ks < 4; ks++)
        qf[ks] = *(const s16x8*)(Qb + (h * S_LEN + qbase + l31) * 64 + ks * 16 + lh * 8);

    f32x16 O0 = (f32x16)0.f, O1 = (f32x16)0.f;
    float2 lpA; lpA.x = 0.f; lpA.y = 0.f;
    float2 lpB; lpB.x = 0.f; lpB.y = 0.f;

    const int tg    = t & 255;           // position within group
    const int strow = tg >> 2;           // 0..63
    const int stch  = (tg & 3) * 16;

    for (int kt = 0; kt < 32; ++kt) {
        const int kv0 = g * 2048 + kt * 64;
        {
            const unsigned short* ksrc = Kb + (h * S_LEN + kv0 + strow) * 64 + stch;
            const unsigned short* vsrc = Vt + (h * 64 + strow) * S_LEN + kv0 + stch;
            s16x8 k0v = *(const s16x8*)(ksrc);
            s16x8 k1v = *(const s16x8*)(ksrc + 8);
            s16x8 v0v = *(const s16x8*)(vsrc);
            s16x8 v1v = *(const s16x8*)(vsrc + 8);
            *(s16x8*)(Ks  + strow * 72 + stch)     = k0v;
            *(s16x8*)(Ks  + strow * 72 + stch + 8) = k1v;
            *(s16x8*)(Vts + strow * 72 + stch)     = v0v;
            *(s16x8*)(Vts + strow * 72 + stch + 8) = v1v;
        }
        __syncthreads();

        // S^T[kv][q] = K x Q^T  (scores pre-scaled via Q)
        f32x16 S0 = (f32x16)0.f, S1 = (f32x16)0.f;
#pragma unroll
        for (int ks = 0; ks < 4; ks++) {
            s16x8 a0 = *(const s16x8*)(Ks + l31 * 72 + ks * 16 + lh * 8);
            s16x8 a1 = *(const s16x8*)(Ks + (32 + l31) * 72 + ks * 16 + lh * 8);
            S0 = __builtin_amdgcn_mfma_f32_32x32x16_bf16(a0, qf[ks], S0, 0, 0, 0);
            S1 = __builtin_amdgcn_mfma_f32_32x32x16_bf16(a1, qf[ks], S1, 0, 0, 0);
        }

#pragma unroll
        for (int i = 0; i < 16; i += 4) {
            float p0 = __builtin_amdgcn_exp2f(S0[i+0]); S0[i+0] = p0; lpA.x += p0;
            float p1 = __builtin_amdgcn_exp2f(S0[i+1]); S0[i+1] = p1; lpA.y += p1;
            float p2 = __builtin_amdgcn_exp2f(S0[i+2]); S0[i+2] = p2; lpB.x += p2;
            float p3 = __builtin_amdgcn_exp2f(S0[i+3]); S0[i+3] = p3; lpB.y += p3;
        }
#pragma unroll
        for (int i = 0; i < 16; i += 4) {
            float p0 = __builtin_amdgcn_exp2f(S1[i+0]); S1[i+0] = p0; lpA.x += p0;
            float p1 = __builtin_amdgcn_exp2f(S1[i+1]); S1[i+1] = p1; lpA.y += p1;
            float p2 = __builtin_amdgcn_exp2f(S1[i+2]); S1[i+2] = p2; lpB.x += p2;
            float p3 = __builtin_amdgcn_exp2f(S1[i+3]); S1[i+3] = p3; lpB.y += p3;
        }

        // batched P write to Ps[q][kv] (stride 68 shorts; ushort4 = 8B aligned)
#pragma unroll
        for (int gq = 0; gq < 4; ++gq) {
            *(ushort4*)(Pw + gq * 8 + lh * 4)      = pkbf4(S0[gq*4], S0[gq*4+1], S0[gq*4+2], S0[gq*4+3]);
            *(ushort4*)(Pw + 32 + gq * 8 + lh * 4) = pkbf4(S1[gq*4], S1[gq*4+1], S1[gq*4+2], S1[gq*4+3]);
        }

        // O^T[d][q] += V^T x P^T
#pragma unroll
        for (int ks = 0; ks < 4; ks++) {
            union { s16x8 v; ushort4 q[2]; } pu;
            pu.q[0] = *(const ushort4*)(Pw + ks * 16 + lh * 8);
            pu.q[1] = *(const ushort4*)(Pw + ks * 16 + lh * 8 + 4);
            s16x8 av0 = *(const s16x8*)(Vts + l31 * 72 + ks * 16 + lh * 8);
            s16x8 av1 = *(const s16x8*)(Vts + (32 + l31) * 72 + ks * 16 + lh * 8);
            O0 = __builtin_amdgcn_mfma_f32_32x32x16_bf16(av0, pu.v, O0, 0, 0, 0);
            O1 = __builtin_amdgcn_mfma_f32_32x32x16_bf16(av1, pu.v, O1, 0, 0, 0);
        }
        __syncthreads();
    }

    // per-wave l partial for q = qbase + l31
    float l_part = (lpA.x + lpA.y) + (lpB.x + lpB.y);
    float l_tot = l_part + __shfl_xor(l_part, 32);
    if (lh == 0) lArr[w * 32 + l31] = l_tot;

    // stash raw O^T (fp32) per wave: Lo[w][q 0..31][d 0..67(pad)]
    float* Lo = (float*)sm + w * 2176;
#pragma unroll
    for (int dt = 0; dt < 2; ++dt) {
        const f32x16& Ox = dt ? O1 : O0;
#pragma unroll
        for (int gq = 0; gq < 4; ++gq) {
            int d0 = dt * 32 + gq * 8 + lh * 4;
            float4 vv;
            vv.x = Ox[gq*4+0]; vv.y = Ox[gq*4+1]; vv.z = Ox[gq*4+2]; vv.w = Ox[gq*4+3];
            *(float4*)(Lo + l31 * 68 + d0) = vv;
        }
    }
    __syncthreads();

    // waves 0-3: combine the two kv-half partials, normalize, store
    if (w < 4) {
        const float* LoA = (float*)sm + w * 2176;
        const float* LoB = (float*)sm + (w + 4) * 2176;
#pragma unroll
        for (int it = 0; it < 8; ++it) {
            int ql = it * 4 + (l >> 4);
            float invl = 1.0f / (lArr[w * 32 + ql] + lArr[(w + 4) * 32 + ql]);
            float4 a = *(const float4*)(LoA + ql * 68 + (l & 15) * 4);
            float4 b = *(const float4*)(LoB + ql * 68 + (l & 15) * 4);
            float4 vv;
            vv.x = (a.x + b.x) * invl;
            vv.y = (a.y + b.y) * invl;
            vv.z = (a.z + b.z) * invl;
            vv.w = (a.w + b.w) * invl;
            *(float4*)(out + (qblk * 128 + w * 32 + ql) * 1024 + h * 64 + (l & 15) * 4) = vv;
        }
    }
}

extern "C" void kernel_launch(void* const* d_in, const int* in_sizes, int n_in,
                              void* d_out, int out_size, void* d_ws, size_t ws_size,
                              hipStream_t stream) {
    const float* X     = (const float*)d_in[0];   // [1,4096,1024]
    const float* W     = (const float*)d_in[1];   // [3072,1024]
    const float* bias  = (const float*)d_in[2];   // [3072]
    const float* trace = (const float*)d_in[3];   // [16,64,64]
    float* out = (float*)d_out;

    unsigned short* Qb = (unsigned short*)d_ws;            // 8 MiB [h][s][d] (pre-scaled by CEXP)
    unsigned short* Kb = Qb + 4194304;                     // 8 MiB [h][s][d]
    unsigned short* Vt = Kb + 4194304;                     // 8 MiB [h][d][s] (pre-scaled by trace diag)
    unsigned short* Xb = Vt + 4194304;                     // 8 MiB bf16 X
    unsigned short* Wb = Xb + 4194304;                     // 6 MiB bf16 W

    const size_t NEED_BF16 = (size_t)3 * 8388608 + 8388608 + 6291456;

    if (ws_size >= NEED_BF16) {
        cvt_bf16<<<3584, 256, 0, stream>>>(X, W, Xb, Wb);
        qkv_gemm_bf16<<<dim3(24, 32), 256, 0, stream>>>(Xb, Wb, bias, trace, Qb, Kb, Vt);
    } else {
        qkv_gemm_f32<<<dim3(24, 32), 256, 0, stream>>>(X, W, bias, trace, Qb, Kb, Vt);
    }
    attn<<<512, 512, 0, stream>>>(Qb, Kb, Vt, out);
}